// Round 5
// baseline (5760.570 us; speedup 1.0000x reference)
//
#include <hip/hip_runtime.h>
#include <hip/hip_fp16.h>

#define B_ 256
#define T_ 1200
#define I_ 16
#define H_ 128

typedef __attribute__((ext_vector_type(2))) _Float16 h2;
typedef __attribute__((ext_vector_type(8))) _Float16 f16x8;

union f16x8u { f16x8 v; h2 h[4]; };

__device__ __forceinline__ float fdot2(h2 a, h2 b, float c) {
  return __builtin_amdgcn_fdot2(a, b, c, false);  // v_dot2_f32_f16
}

// Sum across the 8 lanes of an octet (tid&7), result broadcast to all 8.
__device__ __forceinline__ float qsum8(float x) {
  x += __int_as_float(__builtin_amdgcn_update_dpp(0, __float_as_int(x), 0xB1, 0xF, 0xF, true));   // quad_perm xor1
  x += __int_as_float(__builtin_amdgcn_update_dpp(0, __float_as_int(x), 0x4E, 0xF, 0xF, true));   // quad_perm xor2
  x += __shfl_xor(x, 4);
  return x;
}

__device__ __forceinline__ float sigm(float x) {
  return __builtin_amdgcn_rcpf(1.f + __expf(-x));
}
__device__ __forceinline__ float tanh_(float x) {
  return 1.f - 2.f * __builtin_amdgcn_rcpf(1.f + __expf(2.f * x));
}

// Fully fused 2-layer LSTM + linear head. One WG (1024 thr) per batch row.
// Octet owns output j (j = tid>>3); lane c = tid&7 holds k-slice [16c,16c+16)
// of W_hh0, W_ih1, W_hh1 rows {j, j+128, j+256, j+384} as fp16x2 (~100 VGPRs).
// Layer 1 runs pipelined one step behind layer 0: iteration i computes h0(i)
// AND h1(i-1), both consuming h0(i-1) (single shared LDS read) -> ONE barrier
// per step, 8 independent dot chains per phase.
//
// OCCUPANCY MODEL (fit to rounds 0/3/4): __launch_bounds__ 2nd arg acts like
// CUDA min-BLOCKS-per-CU, and LLVM's RA SPILLS rather than drop below the
// implied waves/EU floor:
//   (512,2) -> 16 waves/CU -> 4/EU floor -> budget 128 (measured 128)
//   (1024,4) -> 64 waves clamp 32 -> 8/EU -> budget 64 (measured 64, spilled)
//   (1024)+waves_per_eu(4,4) -> attr NOT honored for RA budget (measured 64)
// Fix: __launch_bounds__(1024, 1) -> one 16-wave block -> 4 waves/EU floor ->
// 128-VGPR budget; kernel needs ~110 -> fully register-resident, no scratch.
__global__ __launch_bounds__(1024, 1) void lstm_fused(
    const float* __restrict__ xin,
    const float* __restrict__ Wih0, const float* __restrict__ Whh0,
    const float* __restrict__ bih0, const float* __restrict__ bhh0,
    const float* __restrict__ Wih1, const float* __restrict__ Whh1,
    const float* __restrict__ bih1, const float* __restrict__ bhh1,
    const float* __restrict__ Wlin, const float* __restrict__ blin,
    float* __restrict__ out)
{
  __shared__ __align__(16) __half buf0[2][H_];   // h0(t) lives in buf0[t&1]
  __shared__ __align__(16) __half buf1[2][H_];   // h1(t) lives in buf1[t&1]
  __shared__ __align__(16) float red[2][16];     // per-wave head partials

  const int tid = threadIdx.x;
  const int c = tid & 7;      // k-slice lane within octet
  const int j = tid >> 3;     // output row 0..127
  const int b = blockIdx.x;
  const int wv = tid >> 6;    // wave 0..15

  h2 w0[4][8], wi[4][8], wh[4][8], wx[4];  // fp16x2 weight slices
  float bs0[4], bs1[4];

#pragma unroll
  for (int q = 0; q < 4; ++q) {
    const int g = q * H_ + j;
    const float* p0 = Whh0 + g * H_ + c * 16;
    const float* p1 = Wih1 + g * H_ + c * 16;
    const float* p2 = Whh1 + g * H_ + c * 16;
#pragma unroll
    for (int i = 0; i < 4; ++i) {
      float4 v = *(const float4*)(p0 + 4 * i);
      w0[q][2*i].x   = (_Float16)v.x; w0[q][2*i].y   = (_Float16)v.y;
      w0[q][2*i+1].x = (_Float16)v.z; w0[q][2*i+1].y = (_Float16)v.w;
      v = *(const float4*)(p1 + 4 * i);
      wi[q][2*i].x   = (_Float16)v.x; wi[q][2*i].y   = (_Float16)v.y;
      wi[q][2*i+1].x = (_Float16)v.z; wi[q][2*i+1].y = (_Float16)v.w;
      v = *(const float4*)(p2 + 4 * i);
      wh[q][2*i].x   = (_Float16)v.x; wh[q][2*i].y   = (_Float16)v.y;
      wh[q][2*i+1].x = (_Float16)v.z; wh[q][2*i+1].y = (_Float16)v.w;
    }
    const float2 vx = *(const float2*)(Wih0 + g * I_ + 2 * c);
    wx[q].x = (_Float16)vx.x; wx[q].y = (_Float16)vx.y;
    // pre-scaled by 1/8: every lane of the octet seeds its accumulator with
    // bias/8, and qsum8 does a FULL 8-lane sum -> reconstructs the full bias.
    bs0[q] = (bih0[g] + bhh0[g]) * 0.125f;
    bs1[q] = (bih1[g] + bhh1[g]) * 0.125f;
  }
  // NO pre-scale: the head reduction below counts each octet exactly once.
  const float wl = Wlin[j];
  const float bl = blin[0];

  if (tid < H_) {
    const __half z = __float2half(0.f);
    buf0[0][tid] = z; buf0[1][tid] = z;
    buf1[0][tid] = z; buf1[1][tid] = z;
  }
  float cst0 = 0.f, cst1 = 0.f;
  const float* xp = xin + b * (T_ * I_) + 2 * c;
  __syncthreads();

  // Iteration t: layer0 -> h0(t) [t<T], layer1 -> h1(t-1) [t>=1].
  // One barrier per iteration covers all cross-slot hazards.
  for (int t = 0; t <= T_; ++t) {
    const int rb = t & 1;

    // Deferred head store: out[t-2] from partials written in iteration t-1.
    // Rotates across the 16 waves to avoid a fixed straggler.
    if (t >= 2 && tid == (((t - 2) & 15) << 6)) {
      const float4 r0 = *(const float4*)(&red[rb ^ 1][0]);
      const float4 r1 = *(const float4*)(&red[rb ^ 1][4]);
      const float4 r2 = *(const float4*)(&red[rb ^ 1][8]);
      const float4 r3 = *(const float4*)(&red[rb ^ 1][12]);
      out[b * T_ + (t - 2)] = bl +
          r0.x + r0.y + r0.z + r0.w + r1.x + r1.y + r1.z + r1.w +
          r2.x + r2.y + r2.z + r2.w + r3.x + r3.y + r3.z + r3.w;
    }

    float2 xv = make_float2(0.f, 0.f);
    if (t < T_) { xv = *(const float2*)xp; xp += I_; }

    float a0 = bs0[0], a1 = bs0[1], a2 = bs0[2], a3 = bs0[3];
    float b0 = bs1[0], b1 = bs1[1], b2 = bs1[2], b3 = bs1[3];
    const __half* h0p = &buf0[rb ^ 1][c * 16];  // h0(t-1): feeds w0 AND wi
    const __half* h1p = &buf1[rb][c * 16];      // h1(t-2): feeds wh

#pragma unroll
    for (int i = 0; i < 2; ++i) {
      f16x8u u; u.v = *(const f16x8*)(h0p + 8 * i);  // shared broadcast read
#pragma unroll
      for (int p = 0; p < 4; ++p) {
        const h2 hv = u.h[p];
        const int w = 4 * i + p;
        a0 = fdot2(w0[0][w], hv, a0);
        a1 = fdot2(w0[1][w], hv, a1);
        a2 = fdot2(w0[2][w], hv, a2);
        a3 = fdot2(w0[3][w], hv, a3);
        b0 = fdot2(wi[0][w], hv, b0);
        b1 = fdot2(wi[1][w], hv, b1);
        b2 = fdot2(wi[2][w], hv, b2);
        b3 = fdot2(wi[3][w], hv, b3);
      }
    }
#pragma unroll
    for (int i = 0; i < 2; ++i) {
      f16x8u u; u.v = *(const f16x8*)(h1p + 8 * i);
#pragma unroll
      for (int p = 0; p < 4; ++p) {
        const h2 hv = u.h[p];
        const int w = 4 * i + p;
        b0 = fdot2(wh[0][w], hv, b0);
        b1 = fdot2(wh[1][w], hv, b1);
        b2 = fdot2(wh[2][w], hv, b2);
        b3 = fdot2(wh[3][w], hv, b3);
      }
    }
    h2 xa; xa.x = (_Float16)xv.x; xa.y = (_Float16)xv.y;
    a0 = fdot2(wx[0], xa, a0);
    a1 = fdot2(wx[1], xa, a1);
    a2 = fdot2(wx[2], xa, a2);
    a3 = fdot2(wx[3], xa, a3);

    if (t < T_) {  // layer-0 state update -> h0(t)
      const float g0 = qsum8(a0), g1 = qsum8(a1), g2 = qsum8(a2), g3 = qsum8(a3);
      const float ig = sigm(g0), fg = sigm(g1), gg = tanh_(g2), og = sigm(g3);
      cst0 = fg * cst0 + ig * gg;
      const float h0v = og * tanh_(cst0);
      if (c == 0) buf0[rb][j] = __float2half(h0v);
    }
    if (t >= 1) {  // layer-1 state update -> h1(t-1) + head partial
      const float g0 = qsum8(b0), g1 = qsum8(b1), g2 = qsum8(b2), g3 = qsum8(b3);
      const float ig = sigm(g0), fg = sigm(g1), gg = tanh_(g2), og = sigm(g3);
      cst1 = fg * cst1 + ig * gg;
      const float h1v = og * tanh_(cst1);
      if (c == 0) buf1[rb ^ 1][j] = __float2half(h1v);
      // head: val is octet-uniform, so xor8/16/32 accumulates each of the
      // wave's 8 octets exactly once -> full Wlin[j], no redundancy scale.
      float val = fmaxf(h1v, 0.f) * wl;
      val += __shfl_xor(val, 8);
      val += __shfl_xor(val, 16);
      val += __shfl_xor(val, 32);
      if ((tid & 63) == 0) red[rb][wv] = val;
    }
    __syncthreads();
  }

  // final head store: out[T-1] from partials written at t = T_
  if (tid == 0) {
    const int s = T_ & 1;
    const float4 r0 = *(const float4*)(&red[s][0]);
    const float4 r1 = *(const float4*)(&red[s][4]);
    const float4 r2 = *(const float4*)(&red[s][8]);
    const float4 r3 = *(const float4*)(&red[s][12]);
    out[b * T_ + (T_ - 1)] = bl +
        r0.x + r0.y + r0.z + r0.w + r1.x + r1.y + r1.z + r1.w +
        r2.x + r2.y + r2.z + r2.w + r3.x + r3.y + r3.z + r3.w;
  }
}

extern "C" void kernel_launch(void* const* d_in, const int* in_sizes, int n_in,
                              void* d_out, int out_size, void* d_ws, size_t ws_size,
                              hipStream_t stream) {
  // Zero-workspace design: d_ws deliberately unused.
  lstm_fused<<<B_, 1024, 0, stream>>>(
      (const float*)d_in[0],
      (const float*)d_in[1], (const float*)d_in[2],
      (const float*)d_in[3], (const float*)d_in[4],
      (const float*)d_in[5], (const float*)d_in[6],
      (const float*)d_in[7], (const float*)d_in[8],
      (const float*)d_in[9], (const float*)d_in[10],
      (float*)d_out);
}

// Round 6
// 2259.898 us; speedup vs baseline: 2.5490x; 2.5490x over previous
//
#include <hip/hip_runtime.h>
#include <hip/hip_fp16.h>

#define B_ 256
#define T_ 1200
#define I_ 16
#define H_ 128

typedef __attribute__((ext_vector_type(2))) _Float16 h2;
typedef __attribute__((ext_vector_type(8))) _Float16 f16x8;

union f16x8u { f16x8 v; h2 h[4]; };

__device__ __forceinline__ float fdot2(h2 a, h2 b, float c) {
  return __builtin_amdgcn_fdot2(a, b, c, false);  // v_dot2_f32_f16
}

// Sum across the 4 lanes of a quad (tid&3), broadcast. Both DPP quad_perm
// stages are HW-proven (round-0 2028us baseline used exactly these).
__device__ __forceinline__ float qsum4(float x) {
  x += __int_as_float(__builtin_amdgcn_update_dpp(0, __float_as_int(x), 0xB1, 0xF, 0xF, true)); // xor 1
  x += __int_as_float(__builtin_amdgcn_update_dpp(0, __float_as_int(x), 0x4E, 0xF, 0xF, true)); // xor 2
  return x;
}

__device__ __forceinline__ float sigm(float x) {
  return __builtin_amdgcn_rcpf(1.f + __expf(-x));
}
__device__ __forceinline__ float tanh_(float x) {
  return 1.f - 2.f * __builtin_amdgcn_rcpf(1.f + __expf(2.f * x));
}

// Fused 2-layer LSTM + linear head. One WG (512 thr) per batch row.
// Quad owns output j (j=tid>>2); lane c=tid&3 holds k-slice [32c,32c+32) of
// W_hh0, W_ih1, W_hh1 rows {j,j+128,j+256,j+384} as fp16x2 (192 VGPRs).
// Layer 1 pipelined one step behind layer 0 (round-2-proven structure):
// iteration t computes h0(t) AND h1(t-1), both consuming h0(t-1) via one
// shared LDS read -> ONE barrier/step, 8 independent dot chains.
//
// REGISTER-BUDGET LAW (rounds 0-5 measured): 1024-thr kernels are capped at
// 64 VGPRs regardless of launch_bounds/waves_per_eu (weights -> scratch,
// ~500B/thread reloaded per step through L1 = the 5.4ms). The only config
// that moved the budget: 512 thr, where (512,2) -> 128. Blocks-model says
// (512,1) -> 8 waves/CU -> 2 waves/EU -> 256-VGPR budget; need ~230 ->
// fully register-resident. Downside bounded: if capped at 128 we get
// round-0-like spill (~2ms), not 5.4ms.
__global__ __launch_bounds__(512, 1)
__attribute__((amdgpu_waves_per_eu(2))) void lstm_fused(
    const float* __restrict__ xin,
    const float* __restrict__ Wih0, const float* __restrict__ Whh0,
    const float* __restrict__ bih0, const float* __restrict__ bhh0,
    const float* __restrict__ Wih1, const float* __restrict__ Whh1,
    const float* __restrict__ bih1, const float* __restrict__ bhh1,
    const float* __restrict__ Wlin, const float* __restrict__ blin,
    float* __restrict__ out)
{
  __shared__ __align__(16) __half buf0[2][H_];   // h0(t) lives in buf0[t&1]
  __shared__ __align__(16) __half buf1[2][H_];   // h1(t) lives in buf1[t&1]
  __shared__ __align__(16) float red[2][8];      // per-wave head partials

  const int tid = threadIdx.x;
  const int c = tid & 3;      // k-slice lane within quad
  const int j = tid >> 2;     // output row 0..127
  const int b = blockIdx.x;
  const int wv = tid >> 6;    // wave 0..7

  h2 w0[4][16], wi[4][16], wh[4][16], wx[4][2];  // fp16x2 weights (~200 regs)
  float bs0[4], bs1[4];

#pragma unroll
  for (int q = 0; q < 4; ++q) {
    const int g = q * H_ + j;
    const float* p0 = Whh0 + g * H_ + c * 32;
    const float* p1 = Wih1 + g * H_ + c * 32;
    const float* p2 = Whh1 + g * H_ + c * 32;
#pragma unroll
    for (int i = 0; i < 8; ++i) {
      float4 v = *(const float4*)(p0 + 4 * i);
      w0[q][2*i].x   = (_Float16)v.x; w0[q][2*i].y   = (_Float16)v.y;
      w0[q][2*i+1].x = (_Float16)v.z; w0[q][2*i+1].y = (_Float16)v.w;
      v = *(const float4*)(p1 + 4 * i);
      wi[q][2*i].x   = (_Float16)v.x; wi[q][2*i].y   = (_Float16)v.y;
      wi[q][2*i+1].x = (_Float16)v.z; wi[q][2*i+1].y = (_Float16)v.w;
      v = *(const float4*)(p2 + 4 * i);
      wh[q][2*i].x   = (_Float16)v.x; wh[q][2*i].y   = (_Float16)v.y;
      wh[q][2*i+1].x = (_Float16)v.z; wh[q][2*i+1].y = (_Float16)v.w;
    }
    const float4 vx = *(const float4*)(Wih0 + g * I_ + 4 * c);
    wx[q][0].x = (_Float16)vx.x; wx[q][0].y = (_Float16)vx.y;
    wx[q][1].x = (_Float16)vx.z; wx[q][1].y = (_Float16)vx.w;
    // bias/4 seeded in every lane of the quad; qsum4 (full 4-lane sum)
    // reconstructs the full bias.
    bs0[q] = (bih0[g] + bhh0[g]) * 0.25f;
    bs1[q] = (bih1[g] + bhh1[g]) * 0.25f;
  }
  // NO pre-scale: head reduction below counts each quad exactly once
  // (val is quad-uniform; xor4/8/16/32 sums the wave's 16 quads once each).
  const float wl = Wlin[j];
  const float bl = blin[0];

  if (tid < H_) {
    const __half z = __float2half(0.f);
    buf0[0][tid] = z; buf0[1][tid] = z;
    buf1[0][tid] = z; buf1[1][tid] = z;
  }
  float cst0 = 0.f, cst1 = 0.f;
  const float* xp = xin + b * (T_ * I_) + 4 * c;
  __syncthreads();

  // Iteration t: layer0 -> h0(t) [t<T], layer1 -> h1(t-1) [t>=1].
  // One barrier per iteration covers all cross-slot hazards (round-2-proven).
  for (int t = 0; t <= T_; ++t) {
    const int rb = t & 1;

    // Deferred head store: out[t-2] from partials written in iteration t-1.
    // Rotates across the 8 waves to avoid a fixed straggler.
    if (t >= 2 && tid == (((t - 2) & 7) << 6)) {
      const float4 r0 = *(const float4*)(&red[rb ^ 1][0]);
      const float4 r1 = *(const float4*)(&red[rb ^ 1][4]);
      out[b * T_ + (t - 2)] = bl +
          r0.x + r0.y + r0.z + r0.w + r1.x + r1.y + r1.z + r1.w;
    }

    float4 xv = make_float4(0.f, 0.f, 0.f, 0.f);
    if (t < T_) { xv = *(const float4*)xp; xp += I_; }

    float a0 = bs0[0], a1 = bs0[1], a2 = bs0[2], a3 = bs0[3];
    float b0 = bs1[0], b1 = bs1[1], b2 = bs1[2], b3 = bs1[3];
    const __half* h0p = &buf0[rb ^ 1][c * 32];  // h0(t-1): feeds w0 AND wi
    const __half* h1p = &buf1[rb][c * 32];      // h1(t-2): feeds wh

#pragma unroll
    for (int i = 0; i < 4; ++i) {
      f16x8u u; u.v = *(const f16x8*)(h0p + 8 * i);  // shared broadcast read
#pragma unroll
      for (int p = 0; p < 4; ++p) {
        const h2 hv = u.h[p];
        const int w = 4 * i + p;
        a0 = fdot2(w0[0][w], hv, a0);
        a1 = fdot2(w0[1][w], hv, a1);
        a2 = fdot2(w0[2][w], hv, a2);
        a3 = fdot2(w0[3][w], hv, a3);
        b0 = fdot2(wi[0][w], hv, b0);
        b1 = fdot2(wi[1][w], hv, b1);
        b2 = fdot2(wi[2][w], hv, b2);
        b3 = fdot2(wi[3][w], hv, b3);
      }
    }
#pragma unroll
    for (int i = 0; i < 4; ++i) {
      f16x8u u; u.v = *(const f16x8*)(h1p + 8 * i);
#pragma unroll
      for (int p = 0; p < 4; ++p) {
        const h2 hv = u.h[p];
        const int w = 4 * i + p;
        b0 = fdot2(wh[0][w], hv, b0);
        b1 = fdot2(wh[1][w], hv, b1);
        b2 = fdot2(wh[2][w], hv, b2);
        b3 = fdot2(wh[3][w], hv, b3);
      }
    }
    h2 xa, xb;
    xa.x = (_Float16)xv.x; xa.y = (_Float16)xv.y;
    xb.x = (_Float16)xv.z; xb.y = (_Float16)xv.w;
    a0 = fdot2(wx[0][0], xa, fdot2(wx[0][1], xb, a0));
    a1 = fdot2(wx[1][0], xa, fdot2(wx[1][1], xb, a1));
    a2 = fdot2(wx[2][0], xa, fdot2(wx[2][1], xb, a2));
    a3 = fdot2(wx[3][0], xa, fdot2(wx[3][1], xb, a3));

    if (t < T_) {  // layer-0 state update -> h0(t)
      const float g0 = qsum4(a0), g1 = qsum4(a1), g2 = qsum4(a2), g3 = qsum4(a3);
      const float ig = sigm(g0), fg = sigm(g1), gg = tanh_(g2), og = sigm(g3);
      cst0 = fg * cst0 + ig * gg;
      const float h0v = og * tanh_(cst0);
      if (c == 0) buf0[rb][j] = __float2half(h0v);
    }
    if (t >= 1) {  // layer-1 state update -> h1(t-1) + head partial
      const float g0 = qsum4(b0), g1 = qsum4(b1), g2 = qsum4(b2), g3 = qsum4(b3);
      const float ig = sigm(g0), fg = sigm(g1), gg = tanh_(g2), og = sigm(g3);
      cst1 = fg * cst1 + ig * gg;
      const float h1v = og * tanh_(cst1);
      if (c == 0) buf1[rb ^ 1][j] = __float2half(h1v);
      // val is quad-uniform; xor4: +neighbor quad, xor8/16/32: +rest of wave.
      // Each of the wave's 16 quads (16 distinct j) counted exactly once.
      float val = fmaxf(h1v, 0.f) * wl;
      val += __shfl_xor(val, 4);
      val += __shfl_xor(val, 8);
      val += __shfl_xor(val, 16);
      val += __shfl_xor(val, 32);
      if ((tid & 63) == 0) red[rb][wv] = val;
    }
    __syncthreads();
  }

  // final head store: out[T-1] from partials written at t = T_
  if (tid == 0) {
    const int s = T_ & 1;
    const float4 r0 = *(const float4*)(&red[s][0]);
    const float4 r1 = *(const float4*)(&red[s][4]);
    out[b * T_ + (T_ - 1)] = bl +
        r0.x + r0.y + r0.z + r0.w + r1.x + r1.y + r1.z + r1.w;
  }
}

extern "C" void kernel_launch(void* const* d_in, const int* in_sizes, int n_in,
                              void* d_out, int out_size, void* d_ws, size_t ws_size,
                              hipStream_t stream) {
  // Zero-workspace design: d_ws deliberately unused.
  lstm_fused<<<B_, 512, 0, stream>>>(
      (const float*)d_in[0],
      (const float*)d_in[1], (const float*)d_in[2],
      (const float*)d_in[3], (const float*)d_in[4],
      (const float*)d_in[5], (const float*)d_in[6],
      (const float*)d_in[7], (const float*)d_in[8],
      (const float*)d_in[9], (const float*)d_in[10],
      (float*)d_out);
}